// Round 5
// baseline (182.243 us; speedup 1.0000x reference)
//
#include <hip/hip_runtime.h>

#define IN_H 512
#define IN_W 512

// One block = 8-row x 256-col strip (32 tiles), all 3 channels.
// Grid: 32 batches * 64 strip-rows * 2 strip-cols = 4096 blocks.
//
// LDS (30,464 B -> 5 blocks/CU):
//  Ys  @     0 : 32 tiles x 68 f64 (tile-major, pad 4)   = 17408
//  CbS @ 17408 : 32 tiles x 18 f64 (4x4 subsampled +2)   =  4608
//  CrS @ 22016 : 32 tiles x 18 f64                       =  4608
//  qt  @ 26624 : 3 ch x 8 cols x 9 double2 {1/q, q}      =  3456
//  Dd  @ 30080 : 8x4 f64 half-DCT table                  =   256
//  Dh  @ 30336 : 8x4 f32 half-DCT table                  =   128
//
// R8 (resubmit; round 4 was an infra failure, no kernel signal):
// epilogue transposes moved from LDS (Vt) to in-register DPP butterflies.
// The 8 threads of a tile are 8 consecutive lanes, so an 8x8 f32 transpose
// = 3 butterfly stages: xor1/xor2 via quad_perm DPP, xor4 via
// row_half_mirror(l^7) o quad_perm[3,2,1,0](l^3). Removes 24 ds_write_b32
// + 6 ds_read_b128 + 9 wave_barrier fences per thread (DS pipe is the
// highest per-CU floor: ~850 cyc/wave x 64 waves ~ 23us) and decouples the
// 3 channel epilogues. Pure data movement -- zero arithmetic change;
// absmax must stay exactly 0.01367188.

__device__ __forceinline__ float dpp_xor1(float x) {
    return __int_as_float(__builtin_amdgcn_mov_dpp(__float_as_int(x), 0xB1, 0xF, 0xF, true));  // quad_perm [1,0,3,2]
}
__device__ __forceinline__ float dpp_xor2(float x) {
    return __int_as_float(__builtin_amdgcn_mov_dpp(__float_as_int(x), 0x4E, 0xF, 0xF, true));  // quad_perm [2,3,0,1]
}
__device__ __forceinline__ float dpp_xor4(float x) {
    int i = __builtin_amdgcn_mov_dpp(__float_as_int(x), 0x141, 0xF, 0xF, true); // row_half_mirror: l^7 within 8
    i     = __builtin_amdgcn_mov_dpp(i,                 0x1B,  0xF, 0xF, true); // quad_perm [3,2,1,0]: l^3
    return __int_as_float(i);
}

__global__ __launch_bounds__(256, 2) void jpeg_kernel(
    const float* __restrict__ in, const float* __restrict__ qz,
    const float* __restrict__ dmtx, float* __restrict__ out)
{
    __shared__ __align__(16) unsigned char smem[30464];
    double*  Ys  = (double*) (smem);
    double*  CbS = (double*) (smem + 17408);
    double*  CrS = (double*) (smem + 22016);
    double2* qt  = (double2*)(smem + 26624);
    double*  Dd  = (double*) (smem + 30080);
    float*   Dh  = (float*)  (smem + 30336);

    const int t   = threadIdx.x;
    const int blk = blockIdx.x;
    const int b   = blk >> 7;
    const int rr  = blk & 127;
    const int row0 = (rr >> 1) << 3;
    const int col0 = (rr & 1) << 8;
    const int chs = IN_H * IN_W;

    // ---- wave-private staging mapping: tile = t>>3 (same as fold's q8!),
    //      half = (t>>2)&1, rowpair s = t&3 ----
    const int tile = t >> 3;          // 0..31, wave w owns 8w..8w+7
    const int h4   = (t >> 2) & 1;    // 4-col half
    const int s    = t & 3;           // row-pair

    // ---- issue pixel loads FIRST (before the table barrier) ----
    const int base = ((b * 3) * IN_H + row0 + 2 * s) * IN_W + col0 + tile * 8 + 4 * h4;
    float4 ra = *(const float4*)(in + base);
    float4 rb = *(const float4*)(in + base + IN_W);
    float4 ga = *(const float4*)(in + base + chs);
    float4 gb = *(const float4*)(in + base + chs + IN_W);
    float4 ba = *(const float4*)(in + base + 2 * chs);
    float4 bb = *(const float4*)(in + base + 2 * chs + IN_W);

    // ---- P0: tables (the ONLY cross-wave data) ----
    if (t < 192) {
        const int c = t >> 6, i = (t >> 3) & 7, l = t & 7;
        double v  = (double)qz[t];
        double t1 = rint((rint(v * 255.0) * 50.0 + 50.0) / 100.0); // true div: .5 ties
        double q  = fmin(fmax(t1, 1.0), 255.0);
        qt[(c * 8 + l) * 9 + i] = make_double2(1.0 / q, q);
    }
    if (t < 32) {
        float dv = dmtx[(t >> 2) * 8 + (t & 3)];   // half table D[i][0..3]
        Dd[t] = (double)dv;
        Dh[t] = dv;
    }
    __syncthreads();   // tables only -- NOT gated on pixel loads

    // ---- P1: RGB->YCbCr (f64), subsample, stage own wave's tiles ----
    {
        float rA[2][4] = {{ra.x,ra.y,ra.z,ra.w},{rb.x,rb.y,rb.z,rb.w}};
        float gA[2][4] = {{ga.x,ga.y,ga.z,ga.w},{gb.x,gb.y,gb.z,gb.w}};
        float bA[2][4] = {{ba.x,ba.y,ba.z,ba.w},{bb.x,bb.y,bb.z,bb.w}};

        double yv[2][4], cbv[2][4], crv[2][4];
        #pragma unroll
        for (int p = 0; p < 2; ++p) {
            #pragma unroll
            for (int k = 0; k < 4; ++k) {
                double R = 255.0 * (double)rA[p][k];
                double G = 255.0 * (double)gA[p][k];
                double B = 255.0 * (double)bA[p][k];
                double y  =  0.299*R + 0.587*G + 0.114*B;
                double cb = -0.168735892*R - 0.331264108*G + 0.5*B + 128.0;
                double cr =  0.5*R - 0.418687589*G - 0.081312411*B + 128.0;
                yv[p][k]  = fmin(fmax(y , 0.0), 255.0) - 128.0;
                cbv[p][k] = fmin(fmax(cb, 0.0), 255.0);
                crv[p][k] = fmin(fmax(cr, 0.0), 255.0);
            }
        }
        #pragma unroll
        for (int p = 0; p < 2; ++p) {
            double* yp = &Ys[tile * 68 + (2*s + p) * 8 + 4 * h4];
            *(double2*)(yp)     = make_double2(yv[p][0], yv[p][1]);
            *(double2*)(yp + 2) = make_double2(yv[p][2], yv[p][3]);
        }
        double m0 = (cbv[0][0]+cbv[0][1]+cbv[1][0]+cbv[1][1])*0.25 - 128.0;
        double m1 = (cbv[0][2]+cbv[0][3]+cbv[1][2]+cbv[1][3])*0.25 - 128.0;
        *(double2*)&CbS[tile * 18 + s * 4 + 2 * h4] = make_double2(m0, m1);
        double n0 = (crv[0][0]+crv[0][1]+crv[1][0]+crv[1][1])*0.25 - 128.0;
        double n1 = (crv[0][2]+crv[0][3]+crv[1][2]+crv[1][3])*0.25 - 128.0;
        *(double2*)&CrS[tile * 18 + s * 4 + 2 * h4] = make_double2(n0, n1);
    }
    __builtin_amdgcn_wave_barrier();   // own-wave DS writes before fold reads

    // ---- per-thread constants ----
    const int q8 = t >> 3;     // tile (== staging tile)
    const int l  = t & 7;      // DCT column (F) / pixel row (I)
    double dl0, dl1, dl2, dl3;  // D[l][0..3]
    {
        double2 dA = *(const double2*)&Dd[l * 4];
        double2 dB = *(const double2*)&Dd[l * 4 + 2];
        dl0 = dA.x; dl1 = dA.y; dl2 = dB.x; dl3 = dB.y;
    }
    const double sgn  = (l & 1) ? -1.0 : 1.0;
    const double dl01 = dl0 + dl1, dl23 = dl2 + dl3;
    const bool sel1 = (l & 1) != 0;
    const bool sel2 = (l & 2) != 0;
    const bool sel4 = (l & 4) != 0;

    // ---- folds for ALL THREE channels (independent chains) ----
    double e20[4], o20[4];
    {
        const double* basep = &Ys[q8 * 68];
        #pragma unroll
        for (int m = 0; m < 4; ++m) {
            double tp[2];
            #pragma unroll
            for (int hh = 0; hh < 2; ++hh) {
                const double* p = basep + (hh ? (7 - m) : m) * 8;
                double2 a0 = *(const double2*)(p);
                double2 a1 = *(const double2*)(p + 2);
                double2 a2 = *(const double2*)(p + 4);
                double2 a3 = *(const double2*)(p + 6);
                double v0 = fma(sgn, a3.y, a0.x);
                double v1 = fma(sgn, a3.x, a0.y);
                double v2 = fma(sgn, a2.y, a1.x);
                double v3 = fma(sgn, a2.x, a1.y);
                tp[hh] = dl0*v0 + dl1*v1 + dl2*v2 + dl3*v3;
            }
            e20[m] = tp[0] + tp[1];
            o20[m] = tp[0] - tp[1];
        }
    }
    double e21[4], o21[4], e22[4], o22[4];
    #pragma unroll
    for (int cc = 0; cc < 2; ++cc) {
        const double* basep = (cc == 0 ? CbS : CrS) + q8 * 18;
        double u4[4];
        #pragma unroll
        for (int j2 = 0; j2 < 4; ++j2) {
            double2 a0 = *(const double2*)(basep + j2 * 4);
            double2 a1 = *(const double2*)(basep + j2 * 4 + 2);
            u4[j2] = dl01 * fma(sgn, a1.y, a0.x) + dl23 * fma(sgn, a1.x, a0.y);
        }
        double ea = u4[0] + u4[3], oa = u4[0] - u4[3];
        double eb = u4[1] + u4[2], ob = u4[1] - u4[2];
        if (cc == 0) { e21[0]=e21[1]=ea; o21[0]=o21[1]=oa; e21[2]=e21[3]=eb; o21[2]=o21[3]=ob; }
        else         { e22[0]=e22[1]=ea; o22[0]=o22[1]=oa; e22[2]=e22[3]=eb; o22[2]=o22[3]=ob; }
    }

    // ---- fused quant: zo[c][i] = Z[i][l], Dd reads shared across channels ----
    float zo[3][8];
    {
        const double2* dd2 = (const double2*)Dd;
        #pragma unroll
        for (int i = 0; i < 8; ++i) {
            double2 dA = dd2[i * 2], dB = dd2[i * 2 + 1];
            #define ZQ(C, E, O) { \
                double a64 = (i & 1) \
                    ? dA.x*O[0] + dA.y*O[1] + dB.x*O[2] + dB.y*O[3] \
                    : dA.x*E[0] + dA.y*E[1] + dB.x*E[2] + dB.y*E[3]; \
                double2 qe = qt[(C * 8 + l) * 9 + i]; \
                zo[C][i] = (float)(rint(a64 * qe.x) * qe.y); }
            ZQ(0, e20, o20)
            ZQ(1, e21, o21)
            ZQ(2, e22, o22)
            #undef ZQ
        }
    }

    // f32 half-table in registers (loaded AFTER the f64 phase to cap pressure)
    const float4* dh4p = (const float4*)Dh;
    float4 d0 = dh4p[0], d1 = dh4p[1], d2 = dh4p[2], d3 = dh4p[3];
    float4 d4 = dh4p[4], d5 = dh4p[5], d6 = dh4p[6], d7 = dh4p[7];

    float acc[3][8];

    // butterfly exchange: t = sel?A:B; tx = xor(t); A = sel?tx:A; B = sel?B:tx
    #define BFLY(XF, SS, A, B) { float _t = (SS) ? (A) : (B); float _tx = XF(_t); \
                                 (A) = (SS) ? _tx : (A); (B) = (SS) ? (B) : _tx; }

    #define EPI(C) { \
        float se0 = zo[C][0]*d0.x + zo[C][2]*d2.x + zo[C][4]*d4.x + zo[C][6]*d6.x; \
        float se1 = zo[C][0]*d0.y + zo[C][2]*d2.y + zo[C][4]*d4.y + zo[C][6]*d6.y; \
        float se2 = zo[C][0]*d0.z + zo[C][2]*d2.z + zo[C][4]*d4.z + zo[C][6]*d6.z; \
        float se3 = zo[C][0]*d0.w + zo[C][2]*d2.w + zo[C][4]*d4.w + zo[C][6]*d6.w; \
        float so0 = zo[C][1]*d1.x + zo[C][3]*d3.x + zo[C][5]*d5.x + zo[C][7]*d7.x; \
        float so1 = zo[C][1]*d1.y + zo[C][3]*d3.y + zo[C][5]*d5.y + zo[C][7]*d7.y; \
        float so2 = zo[C][1]*d1.z + zo[C][3]*d3.z + zo[C][5]*d5.z + zo[C][7]*d7.z; \
        float so3 = zo[C][1]*d1.w + zo[C][3]*d3.w + zo[C][5]*d5.w + zo[C][7]*d7.w; \
        float u0 = se0+so0, u7 = se0-so0; \
        float u1 = se1+so1, u6 = se1-so1; \
        float u2 = se2+so2, u5 = se2-so2; \
        float u3 = se3+so3, u4v = se3-so3; \
        /* 8x8 transpose across the tile's 8 lanes: after, uk = w2[k] */ \
        BFLY(dpp_xor1, sel1, u0, u1)  BFLY(dpp_xor1, sel1, u2, u3) \
        BFLY(dpp_xor1, sel1, u4v, u5) BFLY(dpp_xor1, sel1, u6, u7) \
        BFLY(dpp_xor2, sel2, u0, u2)  BFLY(dpp_xor2, sel2, u1, u3) \
        BFLY(dpp_xor2, sel2, u4v, u6) BFLY(dpp_xor2, sel2, u5, u7) \
        BFLY(dpp_xor4, sel4, u0, u4v) BFLY(dpp_xor4, sel4, u1, u5) \
        BFLY(dpp_xor4, sel4, u2, u6)  BFLY(dpp_xor4, sel4, u3, u7) \
        float re0 = u0*d0.x + u2*d2.x + u4v*d4.x + u6*d6.x; \
        float re1 = u0*d0.y + u2*d2.y + u4v*d4.y + u6*d6.y; \
        float re2 = u0*d0.z + u2*d2.z + u4v*d4.z + u6*d6.z; \
        float re3 = u0*d0.w + u2*d2.w + u4v*d4.w + u6*d6.w; \
        float ro0 = u1*d1.x + u3*d3.x + u5*d5.x + u7*d7.x; \
        float ro1 = u1*d1.y + u3*d3.y + u5*d5.y + u7*d7.y; \
        float ro2 = u1*d1.z + u3*d3.z + u5*d5.z + u7*d7.z; \
        float ro3 = u1*d1.w + u3*d3.w + u5*d5.w + u7*d7.w; \
        acc[C][0]=re0+ro0; acc[C][7]=re0-ro0; \
        acc[C][1]=re1+ro1; acc[C][6]=re1-ro1; \
        acc[C][2]=re2+ro2; acc[C][5]=re2-ro2; \
        acc[C][3]=re3+ro3; acc[C][4]=re3-ro3; }

    EPI(0)
    EPI(1)
    EPI(2)
    #undef EPI
    #undef BFLY

    // ---- RGB convert + row-major float4 stores (thread = pixel row l) ----
    {
        const int obase = ((b * 3) * IN_H + row0 + l) * IN_W + col0 + q8 * 8;
        float R4[8], G4[8], B4[8];
        #pragma unroll
        for (int y = 0; y < 8; ++y) {
            float im0 = acc[0][y] + 128.0f;
            float im1 = acc[1][y];
            float im2 = acc[2][y];
            float R  = fminf(fmaxf(im0 + 1.402f*im2, 0.0f), 255.0f);
            float G  = fminf(fmaxf(im0 - 0.344136286f*im1 - 0.714136286f*im2, 0.0f), 255.0f);
            float Bv = fminf(fmaxf(im0 + 1.772f*im1, 0.0f), 255.0f);
            R4[y] = rintf(R)  * (1.0f/255.0f);
            G4[y] = rintf(G)  * (1.0f/255.0f);
            B4[y] = rintf(Bv) * (1.0f/255.0f);
        }
        *(float4*)(out + obase)               = make_float4(R4[0],R4[1],R4[2],R4[3]);
        *(float4*)(out + obase + 4)           = make_float4(R4[4],R4[5],R4[6],R4[7]);
        *(float4*)(out + obase + chs)         = make_float4(G4[0],G4[1],G4[2],G4[3]);
        *(float4*)(out + obase + chs + 4)     = make_float4(G4[4],G4[5],G4[6],G4[7]);
        *(float4*)(out + obase + 2*chs)       = make_float4(B4[0],B4[1],B4[2],B4[3]);
        *(float4*)(out + obase + 2*chs + 4)   = make_float4(B4[4],B4[5],B4[6],B4[7]);
    }
}

extern "C" void kernel_launch(void* const* d_in, const int* in_sizes, int n_in,
                              void* d_out, int out_size, void* d_ws, size_t ws_size,
                              hipStream_t stream) {
    (void)in_sizes; (void)n_in; (void)out_size; (void)d_ws; (void)ws_size;
    const float* in  = (const float*)d_in[0];
    const float* qz  = (const float*)d_in[1];
    const float* dm  = (const float*)d_in[2];
    float* out = (float*)d_out;
    dim3 grid(4096), blk(256);
    hipLaunchKernelGGL(jpeg_kernel, grid, blk, 0, stream, in, qz, dm, out);
}

// Round 6
// 181.367 us; speedup vs baseline: 1.0048x; 1.0048x over previous
//
#include <hip/hip_runtime.h>

#define IN_H 512
#define IN_W 512

// One block = 8-row x 256-col strip (32 tiles), all 3 channels.
// Grid: 32 batches * 64 strip-rows * 2 strip-cols = 4096 blocks.
//
// LDS (13,056 B -> residency now capped by threads/VGPR, not LDS):
//  CbS @     0 : 32 tiles x 18 f64 (4x4 subsampled +2)   =  4608
//  CrS @  4608 : 32 tiles x 18 f64                       =  4608
//  qt  @  9216 : 3 ch x 8 cols x 9 double2 {1/q, q}      =  3456
//  Dd  @ 12672 : 8x4 f64 half-DCT table                  =   256
//  Dh  @ 12928 : 8x4 f32 half-DCT table                  =   128
//
// R9: Y path fully in registers -- Ys staging (17.4 KB LDS, 4 b128 writes
// + 32 b128 fold reads per thread, each ~120cy latency) is GONE.
// After P1 the tile's 64 Y f64 values live in its 8 lanes (2 rows x 4 cols
// each). Fold: (1) one l^4 DPP exchange gives each lane the missing 4 cols
// of the row it owns (r = 2s+h4); (2) lane computes the full 8-coef
// row-DCT G[r][0..7] (per-row formulation bit-verified in R6);
// (3) 8x8 f64 DPP butterfly transpose (R8-verified network, both dwords)
// -> lane l holds G[0..7][l]; (4) column fold e2/o2 locally.
// Lane->row map r=2s+h4 means slot k holds G[rho(k)][l], rho(k)=2(k&3)+(k>>2);
// e2/o2 indices remapped statically. Zero arithmetic change vs R6/R8.

__device__ __forceinline__ float dpp_xor1(float x) {
    return __int_as_float(__builtin_amdgcn_mov_dpp(__float_as_int(x), 0xB1, 0xF, 0xF, true));  // quad_perm [1,0,3,2]
}
__device__ __forceinline__ float dpp_xor2(float x) {
    return __int_as_float(__builtin_amdgcn_mov_dpp(__float_as_int(x), 0x4E, 0xF, 0xF, true));  // quad_perm [2,3,0,1]
}
__device__ __forceinline__ float dpp_xor4(float x) {
    int i = __builtin_amdgcn_mov_dpp(__float_as_int(x), 0x141, 0xF, 0xF, true); // row_half_mirror: l^7 within 8
    i     = __builtin_amdgcn_mov_dpp(i,                 0x1B,  0xF, 0xF, true); // quad_perm [3,2,1,0]: l^3
    return __int_as_float(i);
}

__device__ __forceinline__ double dpp_xor1_d(double x) {
    union { double d; int i[2]; } u; u.d = x;
    u.i[0] = __builtin_amdgcn_mov_dpp(u.i[0], 0xB1, 0xF, 0xF, true);
    u.i[1] = __builtin_amdgcn_mov_dpp(u.i[1], 0xB1, 0xF, 0xF, true);
    return u.d;
}
__device__ __forceinline__ double dpp_xor2_d(double x) {
    union { double d; int i[2]; } u; u.d = x;
    u.i[0] = __builtin_amdgcn_mov_dpp(u.i[0], 0x4E, 0xF, 0xF, true);
    u.i[1] = __builtin_amdgcn_mov_dpp(u.i[1], 0x4E, 0xF, 0xF, true);
    return u.d;
}
__device__ __forceinline__ double dpp_xor4_d(double x) {
    union { double d; int i[2]; } u; u.d = x;
    u.i[0] = __builtin_amdgcn_mov_dpp(u.i[0], 0x141, 0xF, 0xF, true);
    u.i[0] = __builtin_amdgcn_mov_dpp(u.i[0], 0x1B,  0xF, 0xF, true);
    u.i[1] = __builtin_amdgcn_mov_dpp(u.i[1], 0x141, 0xF, 0xF, true);
    u.i[1] = __builtin_amdgcn_mov_dpp(u.i[1], 0x1B,  0xF, 0xF, true);
    return u.d;
}

__global__ __launch_bounds__(256, 2) void jpeg_kernel(
    const float* __restrict__ in, const float* __restrict__ qz,
    const float* __restrict__ dmtx, float* __restrict__ out)
{
    __shared__ __align__(16) unsigned char smem[13056];
    double*  CbS = (double*) (smem);
    double*  CrS = (double*) (smem + 4608);
    double2* qt  = (double2*)(smem + 9216);
    double*  Dd  = (double*) (smem + 12672);
    float*   Dh  = (float*)  (smem + 12928);

    const int t   = threadIdx.x;
    const int blk = blockIdx.x;
    const int b   = blk >> 7;
    const int rr  = blk & 127;
    const int row0 = (rr >> 1) << 3;
    const int col0 = (rr & 1) << 8;
    const int chs = IN_H * IN_W;

    // ---- wave-private mapping: tile = t>>3 (== fold's q8), half, rowpair ----
    const int tile = t >> 3;          // 0..31, wave w owns 8w..8w+7
    const int h4   = (t >> 2) & 1;    // 4-col half
    const int s    = t & 3;           // row-pair

    // ---- issue pixel loads FIRST (before the table barrier) ----
    const int base = ((b * 3) * IN_H + row0 + 2 * s) * IN_W + col0 + tile * 8 + 4 * h4;
    float4 ra = *(const float4*)(in + base);
    float4 rb = *(const float4*)(in + base + IN_W);
    float4 ga = *(const float4*)(in + base + chs);
    float4 gb = *(const float4*)(in + base + chs + IN_W);
    float4 ba = *(const float4*)(in + base + 2 * chs);
    float4 bb = *(const float4*)(in + base + 2 * chs + IN_W);

    // ---- P0: tables (the ONLY cross-wave data) ----
    if (t < 192) {
        const int c = t >> 6, i = (t >> 3) & 7, l = t & 7;
        double v  = (double)qz[t];
        double t1 = rint((rint(v * 255.0) * 50.0 + 50.0) / 100.0); // true div: .5 ties
        double q  = fmin(fmax(t1, 1.0), 255.0);
        qt[(c * 8 + l) * 9 + i] = make_double2(1.0 / q, q);
    }
    if (t < 32) {
        float dv = dmtx[(t >> 2) * 8 + (t & 3)];   // half table D[i][0..3]
        Dd[t] = (double)dv;
        Dh[t] = dv;
    }
    __syncthreads();   // tables only -- NOT gated on pixel loads

    // ---- P1: RGB->YCbCr (f64); Y stays in registers, chroma means to LDS ----
    double yv[2][4];
    {
        float rA[2][4] = {{ra.x,ra.y,ra.z,ra.w},{rb.x,rb.y,rb.z,rb.w}};
        float gA[2][4] = {{ga.x,ga.y,ga.z,ga.w},{gb.x,gb.y,gb.z,gb.w}};
        float bA[2][4] = {{ba.x,ba.y,ba.z,ba.w},{bb.x,bb.y,bb.z,bb.w}};

        double cbv[2][4], crv[2][4];
        #pragma unroll
        for (int p = 0; p < 2; ++p) {
            #pragma unroll
            for (int k = 0; k < 4; ++k) {
                double R = 255.0 * (double)rA[p][k];
                double G = 255.0 * (double)gA[p][k];
                double B = 255.0 * (double)bA[p][k];
                double y  =  0.299*R + 0.587*G + 0.114*B;
                double cb = -0.168735892*R - 0.331264108*G + 0.5*B + 128.0;
                double cr =  0.5*R - 0.418687589*G - 0.081312411*B + 128.0;
                yv[p][k]  = fmin(fmax(y , 0.0), 255.0) - 128.0;
                cbv[p][k] = fmin(fmax(cb, 0.0), 255.0);
                crv[p][k] = fmin(fmax(cr, 0.0), 255.0);
            }
        }
        double m0 = (cbv[0][0]+cbv[0][1]+cbv[1][0]+cbv[1][1])*0.25 - 128.0;
        double m1 = (cbv[0][2]+cbv[0][3]+cbv[1][2]+cbv[1][3])*0.25 - 128.0;
        *(double2*)&CbS[tile * 18 + s * 4 + 2 * h4] = make_double2(m0, m1);
        double n0 = (crv[0][0]+crv[0][1]+crv[1][0]+crv[1][1])*0.25 - 128.0;
        double n1 = (crv[0][2]+crv[0][3]+crv[1][2]+crv[1][3])*0.25 - 128.0;
        *(double2*)&CrS[tile * 18 + s * 4 + 2 * h4] = make_double2(n0, n1);
    }

    // ---- per-thread constants ----
    const int q8 = t >> 3;     // tile (== staging tile)
    const int l  = t & 7;      // DCT column (F) / pixel row (I)
    const bool sel1 = (l & 1) != 0;
    const bool sel2 = (l & 2) != 0;
    const bool sel4 = (l & 4) != 0;
    const bool hb   = (h4 != 0);

    // ---- Y fold entirely in registers ----
    double e20[4], o20[4];
    {
        // partner (l^4) exchange: send the row the partner computes,
        // receive the missing 4 cols of the row we compute (r = 2s+h4)
        double recv[4];
        #pragma unroll
        for (int k = 0; k < 4; ++k) {
            double x = hb ? yv[0][k] : yv[1][k];
            recv[k] = dpp_xor4_d(x);
        }
        // ev/ov for our row: ev_j = Y[r][j] + Y[r][7-j], ov_j = Y[r][j] - Y[r][7-j]
        double ev[4], ov[4];
        #pragma unroll
        for (int j = 0; j < 4; ++j) {
            double aj = hb ? recv[j]      : yv[0][j];
            double bj = hb ? yv[1][3 - j] : recv[3 - j];
            ev[j] = aj + bj;
            ov[j] = aj - bj;
        }
        // full 8-coef row DCT of our row (R6-verified expression shapes,
        // D via exact cvt of the f32 table, read broadcast from LDS)
        const float4* dh4 = (const float4*)Dh;
        double G[8];
        #pragma unroll
        for (int i = 0; i < 8; ++i) {
            float4 di = dh4[i];
            const double* vv = (i & 1) ? ov : ev;
            G[i] = (double)di.x*vv[0] + (double)di.y*vv[1]
                 + (double)di.z*vv[2] + (double)di.w*vv[3];
        }
        // 8x8 f64 transpose across the tile's 8 lanes (R8 network).
        // Before: lane holds G[rho(l)][0..7], rho(l)=2s+h4.
        // After:  slot k holds G[rho(k)][l].
        #define BFLY64(XF, SS, A, B) { double _t = (SS) ? (A) : (B); double _tx = XF(_t); \
                                       (A) = (SS) ? _tx : (A); (B) = (SS) ? (B) : _tx; }
        BFLY64(dpp_xor1_d, sel1, G[0], G[1])  BFLY64(dpp_xor1_d, sel1, G[2], G[3])
        BFLY64(dpp_xor1_d, sel1, G[4], G[5])  BFLY64(dpp_xor1_d, sel1, G[6], G[7])
        BFLY64(dpp_xor2_d, sel2, G[0], G[2])  BFLY64(dpp_xor2_d, sel2, G[1], G[3])
        BFLY64(dpp_xor2_d, sel2, G[4], G[6])  BFLY64(dpp_xor2_d, sel2, G[5], G[7])
        BFLY64(dpp_xor4_d, sel4, G[0], G[4])  BFLY64(dpp_xor4_d, sel4, G[1], G[5])
        BFLY64(dpp_xor4_d, sel4, G[2], G[6])  BFLY64(dpp_xor4_d, sel4, G[3], G[7])
        #undef BFLY64
        // column fold: e2[m] = G[m][l] + G[7-m][l]; G[r] lives in slot rho^-1(r)
        // rho^-1: 0->0 1->4 2->1 3->5 4->2 5->6 6->3 7->7
        e20[0] = G[0] + G[7];  o20[0] = G[0] - G[7];
        e20[1] = G[4] + G[3];  o20[1] = G[4] - G[3];
        e20[2] = G[1] + G[6];  o20[2] = G[1] - G[6];
        e20[3] = G[5] + G[2];  o20[3] = G[5] - G[2];
    }

    __builtin_amdgcn_wave_barrier();   // own-wave chroma DS writes before fold reads

    double dl0, dl1, dl2, dl3;  // D[l][0..3] (chroma fold only)
    {
        double2 dA = *(const double2*)&Dd[l * 4];
        double2 dB = *(const double2*)&Dd[l * 4 + 2];
        dl0 = dA.x; dl1 = dA.y; dl2 = dB.x; dl3 = dB.y;
    }
    const double sgn  = (l & 1) ? -1.0 : 1.0;
    const double dl01 = dl0 + dl1, dl23 = dl2 + dl3;

    double e21[4], o21[4], e22[4], o22[4];
    #pragma unroll
    for (int cc = 0; cc < 2; ++cc) {
        const double* basep = (cc == 0 ? CbS : CrS) + q8 * 18;
        double u4[4];
        #pragma unroll
        for (int j2 = 0; j2 < 4; ++j2) {
            double2 a0 = *(const double2*)(basep + j2 * 4);
            double2 a1 = *(const double2*)(basep + j2 * 4 + 2);
            u4[j2] = dl01 * fma(sgn, a1.y, a0.x) + dl23 * fma(sgn, a1.x, a0.y);
        }
        double ea = u4[0] + u4[3], oa = u4[0] - u4[3];
        double eb = u4[1] + u4[2], ob = u4[1] - u4[2];
        if (cc == 0) { e21[0]=e21[1]=ea; o21[0]=o21[1]=oa; e21[2]=e21[3]=eb; o21[2]=o21[3]=ob; }
        else         { e22[0]=e22[1]=ea; o22[0]=o22[1]=oa; e22[2]=e22[3]=eb; o22[2]=o22[3]=ob; }
    }

    // ---- fused quant: zo[c][i] = Z[i][l], Dd reads shared across channels ----
    float zo[3][8];
    {
        const double2* dd2 = (const double2*)Dd;
        #pragma unroll
        for (int i = 0; i < 8; ++i) {
            double2 dA = dd2[i * 2], dB = dd2[i * 2 + 1];
            #define ZQ(C, E, O) { \
                double a64 = (i & 1) \
                    ? dA.x*O[0] + dA.y*O[1] + dB.x*O[2] + dB.y*O[3] \
                    : dA.x*E[0] + dA.y*E[1] + dB.x*E[2] + dB.y*E[3]; \
                double2 qe = qt[(C * 8 + l) * 9 + i]; \
                zo[C][i] = (float)(rint(a64 * qe.x) * qe.y); }
            ZQ(0, e20, o20)
            ZQ(1, e21, o21)
            ZQ(2, e22, o22)
            #undef ZQ
        }
    }

    // f32 half-table in registers (loaded AFTER the f64 phase to cap pressure)
    const float4* dh4p = (const float4*)Dh;
    float4 d0 = dh4p[0], d1 = dh4p[1], d2 = dh4p[2], d3 = dh4p[3];
    float4 d4 = dh4p[4], d5 = dh4p[5], d6 = dh4p[6], d7 = dh4p[7];

    float acc[3][8];

    // butterfly exchange: t = sel?A:B; tx = xor(t); A = sel?tx:A; B = sel?B:tx
    #define BFLY(XF, SS, A, B) { float _t = (SS) ? (A) : (B); float _tx = XF(_t); \
                                 (A) = (SS) ? _tx : (A); (B) = (SS) ? (B) : _tx; }

    #define EPI(C) { \
        float se0 = zo[C][0]*d0.x + zo[C][2]*d2.x + zo[C][4]*d4.x + zo[C][6]*d6.x; \
        float se1 = zo[C][0]*d0.y + zo[C][2]*d2.y + zo[C][4]*d4.y + zo[C][6]*d6.y; \
        float se2 = zo[C][0]*d0.z + zo[C][2]*d2.z + zo[C][4]*d4.z + zo[C][6]*d6.z; \
        float se3 = zo[C][0]*d0.w + zo[C][2]*d2.w + zo[C][4]*d4.w + zo[C][6]*d6.w; \
        float so0 = zo[C][1]*d1.x + zo[C][3]*d3.x + zo[C][5]*d5.x + zo[C][7]*d7.x; \
        float so1 = zo[C][1]*d1.y + zo[C][3]*d3.y + zo[C][5]*d5.y + zo[C][7]*d7.y; \
        float so2 = zo[C][1]*d1.z + zo[C][3]*d3.z + zo[C][5]*d5.z + zo[C][7]*d7.z; \
        float so3 = zo[C][1]*d1.w + zo[C][3]*d3.w + zo[C][5]*d5.w + zo[C][7]*d7.w; \
        float u0 = se0+so0, u7 = se0-so0; \
        float u1 = se1+so1, u6 = se1-so1; \
        float u2 = se2+so2, u5 = se2-so2; \
        float u3 = se3+so3, u4v = se3-so3; \
        /* 8x8 transpose across the tile's 8 lanes: after, uk = w2[k] */ \
        BFLY(dpp_xor1, sel1, u0, u1)  BFLY(dpp_xor1, sel1, u2, u3) \
        BFLY(dpp_xor1, sel1, u4v, u5) BFLY(dpp_xor1, sel1, u6, u7) \
        BFLY(dpp_xor2, sel2, u0, u2)  BFLY(dpp_xor2, sel2, u1, u3) \
        BFLY(dpp_xor2, sel2, u4v, u6) BFLY(dpp_xor2, sel2, u5, u7) \
        BFLY(dpp_xor4, sel4, u0, u4v) BFLY(dpp_xor4, sel4, u1, u5) \
        BFLY(dpp_xor4, sel4, u2, u6)  BFLY(dpp_xor4, sel4, u3, u7) \
        float re0 = u0*d0.x + u2*d2.x + u4v*d4.x + u6*d6.x; \
        float re1 = u0*d0.y + u2*d2.y + u4v*d4.y + u6*d6.y; \
        float re2 = u0*d0.z + u2*d2.z + u4v*d4.z + u6*d6.z; \
        float re3 = u0*d0.w + u2*d2.w + u4v*d4.w + u6*d6.w; \
        float ro0 = u1*d1.x + u3*d3.x + u5*d5.x + u7*d7.x; \
        float ro1 = u1*d1.y + u3*d3.y + u5*d5.y + u7*d7.y; \
        float ro2 = u1*d1.z + u3*d3.z + u5*d5.z + u7*d7.z; \
        float ro3 = u1*d1.w + u3*d3.w + u5*d5.w + u7*d7.w; \
        acc[C][0]=re0+ro0; acc[C][7]=re0-ro0; \
        acc[C][1]=re1+ro1; acc[C][6]=re1-ro1; \
        acc[C][2]=re2+ro2; acc[C][5]=re2-ro2; \
        acc[C][3]=re3+ro3; acc[C][4]=re3-ro3; }

    EPI(0)
    EPI(1)
    EPI(2)
    #undef EPI
    #undef BFLY

    // ---- RGB convert + row-major float4 stores (thread = pixel row l) ----
    {
        const int obase = ((b * 3) * IN_H + row0 + l) * IN_W + col0 + q8 * 8;
        float R4[8], G4[8], B4[8];
        #pragma unroll
        for (int y = 0; y < 8; ++y) {
            float im0 = acc[0][y] + 128.0f;
            float im1 = acc[1][y];
            float im2 = acc[2][y];
            float R  = fminf(fmaxf(im0 + 1.402f*im2, 0.0f), 255.0f);
            float G  = fminf(fmaxf(im0 - 0.344136286f*im1 - 0.714136286f*im2, 0.0f), 255.0f);
            float Bv = fminf(fmaxf(im0 + 1.772f*im1, 0.0f), 255.0f);
            R4[y] = rintf(R)  * (1.0f/255.0f);
            G4[y] = rintf(G)  * (1.0f/255.0f);
            B4[y] = rintf(Bv) * (1.0f/255.0f);
        }
        *(float4*)(out + obase)               = make_float4(R4[0],R4[1],R4[2],R4[3]);
        *(float4*)(out + obase + 4)           = make_float4(R4[4],R4[5],R4[6],R4[7]);
        *(float4*)(out + obase + chs)         = make_float4(G4[0],G4[1],G4[2],G4[3]);
        *(float4*)(out + obase + chs + 4)     = make_float4(G4[4],G4[5],G4[6],G4[7]);
        *(float4*)(out + obase + 2*chs)       = make_float4(B4[0],B4[1],B4[2],B4[3]);
        *(float4*)(out + obase + 2*chs + 4)   = make_float4(B4[4],B4[5],B4[6],B4[7]);
    }
}

extern "C" void kernel_launch(void* const* d_in, const int* in_sizes, int n_in,
                              void* d_out, int out_size, void* d_ws, size_t ws_size,
                              hipStream_t stream) {
    (void)in_sizes; (void)n_in; (void)out_size; (void)d_ws; (void)ws_size;
    const float* in  = (const float*)d_in[0];
    const float* qz  = (const float*)d_in[1];
    const float* dm  = (const float*)d_in[2];
    float* out = (float*)d_out;
    dim3 grid(4096), blk(256);
    hipLaunchKernelGGL(jpeg_kernel, grid, blk, 0, stream, in, qz, dm, out);
}